// Round 11
// baseline (175.603 us; speedup 1.0000x reference)
//
#include <hip/hip_runtime.h>

#define B_ 2
#define T_ 2048
#define C_ 1024
#define H_ 16
#define DH_ 64

typedef __attribute__((ext_vector_type(8))) _Float16 half8;  // 8 f16 (4 VGPRs)
typedef __attribute__((ext_vector_type(4))) _Float16 half4;  // 4 f16 (2 VGPRs)
typedef __attribute__((ext_vector_type(2))) __fp16 fp16x2;   // cvt_pkrtz result type
typedef __attribute__((ext_vector_type(4))) float f32x4;
typedef __attribute__((ext_vector_type(16))) float f32x16;

__device__ __forceinline__ unsigned short f2h(float f) {
    union { _Float16 h; unsigned short u; } cv; cv.h = (_Float16)f; return cv.u;
}
__device__ __forceinline__ unsigned pk2(float a, float b) {
    union { fp16x2 h; unsigned u; } cv;
    cv.h = __builtin_amdgcn_cvt_pkrtz(a, b);
    return cv.u;
}
// swap lanes 32-63 of a with lanes 0-31 of b (gfx950)
__device__ __forceinline__ void plswap(unsigned &a, unsigned &b) {
    asm volatile("v_permlane32_swap_b32 %0, %1" : "+v"(a), "+v"(b));
}

__device__ __forceinline__ void gll16(const void* g, void* l) {
    __builtin_amdgcn_global_load_lds(
        (const __attribute__((address_space(1))) void*)g,
        (__attribute__((address_space(3))) void*)l, 16, 0, 0);
}

// ---------------------------------------------------------------------------
// Prep (single launch): blocks [0,2048): x fp32->fp16 (+mask vec in block 0);
// blocks [2048, 5120): W transpose+convert -> Wt[z] (fp16 [N][K]).
// ---------------------------------------------------------------------------
__global__ __launch_bounds__(256) void prep_kernel(
    const float* __restrict__ x, unsigned short* __restrict__ xf,
    const int* __restrict__ mask, unsigned short* __restrict__ mb,
    const float* __restrict__ Wq, const float* __restrict__ Wk,
    const float* __restrict__ Wv, unsigned short* __restrict__ wt)
{
    __shared__ float tile[32][33];
    const int tid = threadIdx.x;

    if (blockIdx.x < 2048) {
        const size_t idx8 = ((size_t)blockIdx.x * 256 + tid) * 8;
        float4 v0 = *(const float4*)(x + idx8);
        float4 v1 = *(const float4*)(x + idx8 + 4);
        float f[8] = {v0.x, v0.y, v0.z, v0.w, v1.x, v1.y, v1.z, v1.w};
        unsigned short h[8];
#pragma unroll
        for (int i = 0; i < 8; i++) h[i] = f2h(f[i]);
        *(uint4*)(xf + idx8) = *(const uint4*)h;

        if (blockIdx.x == 0) {
#pragma unroll
            for (int j = 0; j < 16; j++) {
                int i = tid * 16 + j;               // covers B_*T_ = 4096
                mb[i] = (mask[i] != 0) ? (unsigned short)0x3C00 : (unsigned short)0;
            }
        }
    } else {
        const int idx = blockIdx.x - 2048;
        const int z   = idx >> 10;
        const int rem = idx & 1023;
        const int n0  = (rem & 31) * 32;
        const int k0  = (rem >> 5) * 32;
        const float* __restrict__ W = (z == 0) ? Wq : (z == 1) ? Wk : Wv;
        unsigned short* __restrict__ wtz = wt + (size_t)z * C_ * C_;
        const int tx = tid & 31;
        const int ty = tid >> 5;                    // 0..7
#pragma unroll
        for (int j = 0; j < 4; j++)
            tile[ty + j * 8][tx] = W[(size_t)(k0 + ty + j * 8) * C_ + n0 + tx];
        __syncthreads();
#pragma unroll
        for (int j = 0; j < 4; j++)
            wtz[(size_t)(n0 + ty + j * 8) * C_ + k0 + tx] = f2h(tile[tx][ty + j * 8]);
    }
}

// ---------------------------------------------------------------------------
// QKV projection R22 (session-best form): 2D XCD tiling (8 tok x 12 yz per
// XCD) + double-buffered LDS (64KB): barrier -> issue STAGE(t+1) -> compute(t).
// R25's counted-vmcnt asm barrier regressed (opaque wall blocked the
// compiler's ds_read/MFMA interleave) — keep the plain-barrier form.
// ---------------------------------------------------------------------------
__global__ __launch_bounds__(256) void qkv_mfma_kernel(
    const unsigned short* __restrict__ xf, const unsigned short* __restrict__ wt,
    const float* __restrict__ bq, const float* __restrict__ bk,
    const float* __restrict__ bv, const int* __restrict__ maskp,
    unsigned short* __restrict__ qb, unsigned short* __restrict__ kb,
    unsigned short* __restrict__ vt)
{
    __shared__ unsigned short sX[2][128 * 64];
    __shared__ unsigned short sW[2][128 * 64];

    const int bid  = blockIdx.x;
    const int xcd  = bid & 7;            // HW: block bid runs on XCD bid%8
    const int idx  = bid >> 3;           // 0..95 within XCD
    const int tokl = idx / 12;           // 0..7  (tok-local, outer)
    const int yzl  = idx % 12;           // 0..11 (yz-local, inner -> W hot)
    const int tokb = (xcd >> 1) * 8 + tokl;   // 0..31
    const int yz   = (xcd & 1) * 12 + yzl;    // 0..23
    const int z    = yz >> 3;            // 0..2
    const int yb   = yz & 7;             // 0..7

    const float* __restrict__ bias = (z == 0) ? bq : (z == 1) ? bk : bv;
    const unsigned short* __restrict__ wtz = wt + (size_t)z * C_ * C_;

    const int tok0 = tokb * 128;
    const int col0 = yb * 128;
    const int wv    = threadIdx.x >> 6;
    const int lane  = threadIdx.x & 63;
    const int l15   = lane & 15;
    const int quad  = lane >> 4;
    const int l7    = l15 & 7;
    const int wm    = wv >> 1;
    const int wn    = wv & 1;
    const int lrow8 = lane >> 3;
    const int gch   = (lane & 7) ^ lrow8;

    f32x4 acc[4][4];
#pragma unroll
    for (int i = 0; i < 4; i++)
#pragma unroll
        for (int j = 0; j < 4; j++) acc[i][j] = (f32x4){0.f, 0.f, 0.f, 0.f};

    int aoff[4][2], boff[4][2];
#pragma unroll
    for (int i = 0; i < 4; i++)
#pragma unroll
        for (int s = 0; s < 2; s++) {
            aoff[i][s] = (wm * 64 + i * 16 + l15) * 64 + (((s * 4 + quad) ^ l7) * 8);
            boff[i][s] = (wn * 64 + i * 16 + l15) * 64 + (((s * 4 + quad) ^ l7) * 8);
        }

#define STAGE_QKV(k0v, bi) do {                                               \
    _Pragma("unroll")                                                         \
    for (int s = 0; s < 8; ++s) {                                             \
        int g    = (s << 2) + wv;                                             \
        int tsel = g >> 4;                                                    \
        int r0   = (g & 15) << 3;                                             \
        const unsigned short* src = tsel ? wtz : xf;                          \
        unsigned short*       dst = tsel ? &sW[bi][0] : &sX[bi][0];           \
        int rowg = tsel ? col0 : tok0;                                        \
        gll16(src + (size_t)(rowg + r0 + lrow8) * C_ + (k0v) + gch * 8,       \
              dst + r0 * 64);                                                 \
    }                                                                         \
} while (0)

    STAGE_QKV(0, 0);

    for (int k0 = 0; k0 < C_; k0 += 64) {
        const int cur = (k0 >> 6) & 1;
        __syncthreads();                 // drains vmcnt(0): buf[cur] ready
        if (k0 + 64 < C_) STAGE_QKV(k0 + 64, cur ^ 1);

        const unsigned short* Abuf = (z < 2) ? &sX[cur][0] : &sW[cur][0];
        const unsigned short* Bbuf = (z < 2) ? &sW[cur][0] : &sX[cur][0];

        half8 af[4][2], bf_[4][2];
#pragma unroll
        for (int i = 0; i < 4; i++)
#pragma unroll
            for (int s = 0; s < 2; s++) {
                af[i][s]  = *(const half8*)&Abuf[aoff[i][s]];
                bf_[i][s] = *(const half8*)&Bbuf[boff[i][s]];
            }
#pragma unroll
        for (int s = 0; s < 2; s++)
#pragma unroll
            for (int j = 0; j < 4; j++)
#pragma unroll
                for (int i = 0; i < 4; i++)
                    acc[i][j] = __builtin_amdgcn_mfma_f32_16x16x32_f16(
                        af[i][s], bf_[j][s], acc[i][j], 0, 0, 0);
    }
#undef STAGE_QKV

    if (z == 0) {
#pragma unroll
        for (int j = 0; j < 4; j++) {
            int col = col0 + wn * 64 + j * 16 + l15;
            int h = col >> 6, d = col & 63;
            float bs = bias[col];
#pragma unroll
            for (int i = 0; i < 4; i++) {
#pragma unroll
                for (int r = 0; r < 4; r++) {
                    int tok = tok0 + wm * 64 + i * 16 + quad * 4 + r;
                    int bidx = tok >> 11, t = tok & (T_ - 1);
                    qb[((size_t)(bidx * H_ + h) * T_ + t) * DH_ + d] =
                        f2h((acc[i][j][r] + bs) * 0.18033688011112042f);
                }
            }
        }
    } else if (z == 1) {
#pragma unroll
        for (int j = 0; j < 4; j++) {
            int col = col0 + wn * 64 + j * 16 + l15;
            int h = col >> 6, d = col & 63;
            float bs = bias[col];
#pragma unroll
            for (int i = 0; i < 4; i++) {
#pragma unroll
                for (int r = 0; r < 4; r++) {
                    int tok = tok0 + wm * 64 + i * 16 + quad * 4 + r;
                    int bidx = tok >> 11, t = tok & (T_ - 1);
                    kb[((size_t)(bidx * H_ + h) * T_ + t) * DH_ + d] =
                        f2h(acc[i][j][r] + bs);
                }
            }
        }
    } else {
        float mv4[4]; int bidx4[4], t4[4];
#pragma unroll
        for (int j = 0; j < 4; j++) {
            int tok = tok0 + wn * 64 + j * 16 + l15;
            bidx4[j] = tok >> 11; t4[j] = tok & (T_ - 1);
            mv4[j] = (maskp[bidx4[j] * T_ + t4[j]] != 0) ? 1.f : 0.f;
        }
#pragma unroll
        for (int i = 0; i < 4; i++) {
#pragma unroll
            for (int r = 0; r < 4; r++) {
                int col = col0 + wm * 64 + i * 16 + quad * 4 + r;
                int h = col >> 6, d = col & 63;
                float bs = bias[col];
#pragma unroll
                for (int j = 0; j < 4; j++) {
                    vt[((size_t)(bidx4[j] * H_ + h) * DH_ + d) * T_ + t4[j]] =
                        f2h((acc[i][j][r] + bs) * mv4[j]);
                }
            }
        }
    }
}

// ---------------------------------------------------------------------------
// Attention R27: 64 queries/wave (4 waves x 64 q, grid 32x8 = 1 block/CU).
// Mechanism: attn's elapsed == MFMA+VALU+LDS pipe SUM (additive, verified
// R2/R6/R7). Overlap attacks all failed; this cuts the SUM: each kf/vb LDS
// read now feeds TWO query-tiles (qn=0,1) -> per-CU-kt LDS reads halve
// (128->64 b128), MFMA/VALU totals unchanged. Pipe sum 4000 -> ~3280 cyc/kt.
// Known risk: 1 wave/SIMD (grid-limited) — if intra-wave serialization at
// zero TLP dominates, this regresses and brackets the design space.
// The two qn chains give natural intra-wave ILP in every phase.
// ---------------------------------------------------------------------------
__global__ __launch_bounds__(256, 1) void attn_mfma_kernel(
    const unsigned short* __restrict__ qb,  // [32][2048][64] f16 (pre-scaled)
    const unsigned short* __restrict__ kb,  // [32][2048][64] f16
    const unsigned short* __restrict__ vt,  // [32][64][2048] f16 (mask-zeroed)
    const int* __restrict__ mask,           // [2][2048]
    const unsigned short* __restrict__ mb,  // [2][2048] f16 {0,1}
    float* __restrict__ out)                // [2][2048][1024]
{
    __shared__ unsigned short Ks[2][64 * 64];
    __shared__ unsigned short Vs[2][64 * 64];

    const int bh   = blockIdx.x;            // bh-major: same head -> same XCD
    const int b    = bh >> 4;
    const int h    = bh & 15;
    const int wv   = threadIdx.x >> 6;      // 0..3
    const int lane = threadIdx.x & 63;
    const int l31  = lane & 31;
    const int hi   = lane >> 5;
    const int l7b  = l31 & 7;               // row&7 for swizzled frag reads
    const int q0w  = blockIdx.y * 256 + wv * 64;   // 64 queries per wave

    const unsigned short* kbh = kb + (size_t)bh * T_ * DH_;
    const unsigned short* vbh = vt + (size_t)bh * DH_ * T_;
    const unsigned short* mbb = mb + b * T_;
    const int* __restrict__ mrow = mask + b * T_;

    // Q B-frags (32x32x16), two query-tiles qn: lane n = qn*32+l31, k chunks m
    half8 qf[2][4];
#pragma unroll
    for (int qn = 0; qn < 2; ++qn)
#pragma unroll
        for (int m = 0; m < 4; ++m)
            qf[qn][m] = *(const half8*)(qb + ((size_t)bh * T_ + q0w + qn * 32 + l31) * DH_
                                        + m * 16 + hi * 8);

    f32x16 o[2][2], lacc[2];
#pragma unroll
    for (int qn = 0; qn < 2; ++qn) {
#pragma unroll
        for (int r = 0; r < 16; ++r) { o[qn][0][r] = 0.f; o[qn][1][r] = 0.f; lacc[qn][r] = 0.f; }
    }

    const int lrow = lane >> 3;
    const int gch  = (lane & 7) ^ lrow;

#pragma unroll
    for (int s = 0; s < 4; ++s) {
        int j  = (wv << 2) + s;
        int rb = j & 7;
        if (j < 8) gll16(kbh + (size_t)(rb * 8 + lrow) * DH_ + gch * 8, &Ks[0][rb * 512]);
        else       gll16(vbh + (size_t)(rb * 8 + lrow) * T_  + gch * 8, &Vs[0][rb * 512]);
    }

    for (int kt = 0; kt < 32; ++kt) {
        const int cur   = kt & 1;
        const int kbase = kt * 64;
        __syncthreads();

        if (kt < 31) {
            const int nb = kbase + 64;
#pragma unroll
            for (int s = 0; s < 4; ++s) {
                int j  = (wv << 2) + s;
                int rb = j & 7;
                if (j < 8) gll16(kbh + (size_t)(nb + rb * 8 + lrow) * DH_ + gch * 8,
                                 &Ks[cur ^ 1][rb * 512]);
                else       gll16(vbh + (size_t)(rb * 8 + lrow) * T_ + nb + gch * 8,
                                 &Vs[cur ^ 1][rb * 512]);
            }
        }

        const unsigned short* Kc = &Ks[cur][0];
        const unsigned short* Vc = &Vs[cur][0];

        // mask B-frags for l-sum: every column n holds m[k]; shared across qn
        half8 bm[4];
#pragma unroll
        for (int c = 0; c < 4; ++c)
            bm[c] = *(const half8*)(mbb + kbase + c * 16 + hi * 8);

        // S^T = K . Q^T per 32-key tile; kf read ONCE, feeds both qn tiles.
        half8 pa[2][4];
#pragma unroll
        for (int st = 0; st < 2; ++st) {
            half8 kf[4];
#pragma unroll
            for (int m = 0; m < 4; ++m)
                kf[m] = *(const half8*)(Kc + (st * 32 + l31) * 64
                                        + (((m * 2 + hi) ^ l7b) * 8));
#pragma unroll
            for (int qn = 0; qn < 2; ++qn) {
                f32x16 sa;
#pragma unroll
                for (int r = 0; r < 16; ++r) sa[r] = 0.f;
#pragma unroll
                for (int m = 0; m < 4; ++m)
                    sa = __builtin_amdgcn_mfma_f32_32x32x16_f16(kf[m], qf[qn][m], sa, 0, 0, 0);
                float p[16];
#pragma unroll
                for (int r = 0; r < 16; ++r) p[r] = __builtin_amdgcn_exp2f(sa[r]);
                // C-layout k of reg r (rel. 16-key chunk): (r&3)+8*(r>>2)+4*hi.
                // swap(pk(p0,p1),pk(p4,p5))->w0,w2 ; swap(pk(p2,p3),pk(p6,p7))->w1,w3
#pragma unroll
                for (int kh = 0; kh < 2; ++kh) {
                    unsigned w0 = pk2(p[kh * 8 + 0], p[kh * 8 + 1]);
                    unsigned w2 = pk2(p[kh * 8 + 4], p[kh * 8 + 5]);
                    unsigned w1 = pk2(p[kh * 8 + 2], p[kh * 8 + 3]);
                    unsigned w3 = pk2(p[kh * 8 + 6], p[kh * 8 + 7]);
                    plswap(w0, w2);
                    plswap(w1, w3);
                    union { unsigned u[4]; half8 hh; } cv;
                    cv.u[0] = w0; cv.u[1] = w1; cv.u[2] = w2; cv.u[3] = w3;
                    pa[qn][st * 2 + kh] = cv.hh;
                }
            }
        }

        // l += P . maskcol (per qn tile)
#pragma unroll
        for (int qn = 0; qn < 2; ++qn)
#pragma unroll
            for (int c = 0; c < 4; ++c)
                lacc[qn] = __builtin_amdgcn_mfma_f32_32x32x16_f16(pa[qn][c], bm[c],
                                                                  lacc[qn], 0, 0, 0);

        // O += P V: each v0/v1 LDS read feeds BOTH qn tiles (the new reuse)
#pragma unroll
        for (int c = 0; c < 4; ++c) {
            half8 v0 = *(const half8*)(Vc + (l31) * 64      + (((c * 2 + hi) ^ l7b) * 8));
            half8 v1 = *(const half8*)(Vc + (32 + l31) * 64 + (((c * 2 + hi) ^ l7b) * 8));
#pragma unroll
            for (int qn = 0; qn < 2; ++qn) {
                o[qn][0] = __builtin_amdgcn_mfma_f32_32x32x16_f16(pa[qn][c], v0, o[qn][0], 0, 0, 0);
                o[qn][1] = __builtin_amdgcn_mfma_f32_32x32x16_f16(pa[qn][c], v1, o[qn][1], 0, 0, 0);
            }
        }
    }

    // Epilogue: C row r -> q = q0w + qn*32 + (r&3)+8*(r>>2)+4*hi; l = lacc[qn][r]
#pragma unroll
    for (int qn = 0; qn < 2; ++qn) {
#pragma unroll
        for (int r = 0; r < 16; ++r) {
            int q = q0w + qn * 32 + (r & 3) + 8 * (r >> 2) + 4 * hi;
            float lv = lacc[qn][r];
            float iv = (mrow[q] != 0 && lv > 0.f) ? (1.0f / lv) : 0.f;
            float* orow = out + ((size_t)(b * T_ + q)) * C_ + h * DH_;
            orow[l31]      = o[qn][0][r] * iv;
            orow[32 + l31] = o[qn][1][r] * iv;
        }
    }
}

// ---------------------------------------------------------------------------
extern "C" void kernel_launch(void* const* d_in, const int* in_sizes, int n_in,
                              void* d_out, int out_size, void* d_ws, size_t ws_size,
                              hipStream_t stream)
{
    (void)in_sizes; (void)n_in; (void)out_size; (void)ws_size;
    const float* x  = (const float*)d_in[0];
    const float* Wq = (const float*)d_in[1];
    const float* bq = (const float*)d_in[2];
    const float* Wk = (const float*)d_in[3];
    const float* bk = (const float*)d_in[4];
    const float* Wv = (const float*)d_in[5];
    const float* bv = (const float*)d_in[6];
    const int* mask = (const int*)d_in[7];
    float* out = (float*)d_out;

    const size_t NX = (size_t)B_ * T_ * C_;          // 4 Mi elements
    unsigned short* xf = (unsigned short*)d_ws;       // 8 MB fp16 x
    unsigned short* wt = xf + NX;                     // 6 MB fp16 W^T x3
    unsigned short* qb = wt + (size_t)3 * C_ * C_;    // 8 MB (pre-scaled q)
    unsigned short* kb = qb + NX;                     // 8 MB
    unsigned short* vt = kb + NX;                     // 8 MB
    unsigned short* mb = vt + NX;                     // 8 KB

    prep_kernel<<<5120, 256, 0, stream>>>(x, xf, mask, mb, Wq, Wk, Wv, wt);
    qkv_mfma_kernel<<<768, 256, 0, stream>>>(
        xf, wt, bq, bk, bv, mask, qb, kb, vt);
    attn_mfma_kernel<<<dim3(32, 8), 256, 0, stream>>>(qb, kb, vt, mask, mb, out);
}

// Round 12
// 172.145 us; speedup vs baseline: 1.0201x; 1.0201x over previous
//
#include <hip/hip_runtime.h>

#define B_ 2
#define T_ 2048
#define C_ 1024
#define H_ 16
#define DH_ 64

typedef __attribute__((ext_vector_type(8))) _Float16 half8;  // 8 f16 (4 VGPRs)
typedef __attribute__((ext_vector_type(4))) _Float16 half4;  // 4 f16 (2 VGPRs)
typedef __attribute__((ext_vector_type(2))) __fp16 fp16x2;   // cvt_pkrtz result type
typedef __attribute__((ext_vector_type(4))) float f32x4;
typedef __attribute__((ext_vector_type(16))) float f32x16;

__device__ __forceinline__ unsigned short f2h(float f) {
    union { _Float16 h; unsigned short u; } cv; cv.h = (_Float16)f; return cv.u;
}
__device__ __forceinline__ unsigned pk2(float a, float b) {
    union { fp16x2 h; unsigned u; } cv;
    cv.h = __builtin_amdgcn_cvt_pkrtz(a, b);
    return cv.u;
}
// swap lanes 32-63 of a with lanes 0-31 of b (gfx950)
__device__ __forceinline__ void plswap(unsigned &a, unsigned &b) {
    asm volatile("v_permlane32_swap_b32 %0, %1" : "+v"(a), "+v"(b));
}

__device__ __forceinline__ void gll16(const void* g, void* l) {
    __builtin_amdgcn_global_load_lds(
        (const __attribute__((address_space(1))) void*)g,
        (__attribute__((address_space(3))) void*)l, 16, 0, 0);
}

// ---------------------------------------------------------------------------
// Prep (single launch): blocks [0,2048): x fp32->fp16 (+mask vec in block 0);
// blocks [2048, 5120): W transpose+convert -> Wt[z] (fp16 [N][K]).
// ---------------------------------------------------------------------------
__global__ __launch_bounds__(256) void prep_kernel(
    const float* __restrict__ x, unsigned short* __restrict__ xf,
    const int* __restrict__ mask, unsigned short* __restrict__ mb,
    const float* __restrict__ Wq, const float* __restrict__ Wk,
    const float* __restrict__ Wv, unsigned short* __restrict__ wt)
{
    __shared__ float tile[32][33];
    const int tid = threadIdx.x;

    if (blockIdx.x < 2048) {
        const size_t idx8 = ((size_t)blockIdx.x * 256 + tid) * 8;
        float4 v0 = *(const float4*)(x + idx8);
        float4 v1 = *(const float4*)(x + idx8 + 4);
        float f[8] = {v0.x, v0.y, v0.z, v0.w, v1.x, v1.y, v1.z, v1.w};
        unsigned short h[8];
#pragma unroll
        for (int i = 0; i < 8; i++) h[i] = f2h(f[i]);
        *(uint4*)(xf + idx8) = *(const uint4*)h;

        if (blockIdx.x == 0) {
#pragma unroll
            for (int j = 0; j < 16; j++) {
                int i = tid * 16 + j;               // covers B_*T_ = 4096
                mb[i] = (mask[i] != 0) ? (unsigned short)0x3C00 : (unsigned short)0;
            }
        }
    } else {
        const int idx = blockIdx.x - 2048;
        const int z   = idx >> 10;
        const int rem = idx & 1023;
        const int n0  = (rem & 31) * 32;
        const int k0  = (rem >> 5) * 32;
        const float* __restrict__ W = (z == 0) ? Wq : (z == 1) ? Wk : Wv;
        unsigned short* __restrict__ wtz = wt + (size_t)z * C_ * C_;
        const int tx = tid & 31;
        const int ty = tid >> 5;                    // 0..7
#pragma unroll
        for (int j = 0; j < 4; j++)
            tile[ty + j * 8][tx] = W[(size_t)(k0 + ty + j * 8) * C_ + n0 + tx];
        __syncthreads();
#pragma unroll
        for (int j = 0; j < 4; j++)
            wtz[(size_t)(n0 + ty + j * 8) * C_ + k0 + tx] = f2h(tile[tx][ty + j * 8]);
    }
}

// ---------------------------------------------------------------------------
// QKV projection R22 (kept from R6): 2D XCD tiling (8 tok x 12 yz per XCD)
// + double-buffered LDS (64KB): barrier -> issue STAGE(t+1) -> compute(t).
// ---------------------------------------------------------------------------
__global__ __launch_bounds__(256) void qkv_mfma_kernel(
    const unsigned short* __restrict__ xf, const unsigned short* __restrict__ wt,
    const float* __restrict__ bq, const float* __restrict__ bk,
    const float* __restrict__ bv, const int* __restrict__ maskp,
    unsigned short* __restrict__ qb, unsigned short* __restrict__ kb,
    unsigned short* __restrict__ vt)
{
    __shared__ unsigned short sX[2][128 * 64];
    __shared__ unsigned short sW[2][128 * 64];

    const int bid  = blockIdx.x;
    const int xcd  = bid & 7;            // HW: block bid runs on XCD bid%8
    const int idx  = bid >> 3;           // 0..95 within XCD
    const int tokl = idx / 12;           // 0..7  (tok-local, outer)
    const int yzl  = idx % 12;           // 0..11 (yz-local, inner -> W hot)
    const int tokb = (xcd >> 1) * 8 + tokl;   // 0..31
    const int yz   = (xcd & 1) * 12 + yzl;    // 0..23
    const int z    = yz >> 3;            // 0..2
    const int yb   = yz & 7;             // 0..7

    const float* __restrict__ bias = (z == 0) ? bq : (z == 1) ? bk : bv;
    const unsigned short* __restrict__ wtz = wt + (size_t)z * C_ * C_;

    const int tok0 = tokb * 128;
    const int col0 = yb * 128;
    const int wv    = threadIdx.x >> 6;
    const int lane  = threadIdx.x & 63;
    const int l15   = lane & 15;
    const int quad  = lane >> 4;
    const int l7    = l15 & 7;
    const int wm    = wv >> 1;
    const int wn    = wv & 1;
    const int lrow8 = lane >> 3;
    const int gch   = (lane & 7) ^ lrow8;

    f32x4 acc[4][4];
#pragma unroll
    for (int i = 0; i < 4; i++)
#pragma unroll
        for (int j = 0; j < 4; j++) acc[i][j] = (f32x4){0.f, 0.f, 0.f, 0.f};

    int aoff[4][2], boff[4][2];
#pragma unroll
    for (int i = 0; i < 4; i++)
#pragma unroll
        for (int s = 0; s < 2; s++) {
            aoff[i][s] = (wm * 64 + i * 16 + l15) * 64 + (((s * 4 + quad) ^ l7) * 8);
            boff[i][s] = (wn * 64 + i * 16 + l15) * 64 + (((s * 4 + quad) ^ l7) * 8);
        }

#define STAGE_QKV(k0v, bi) do {                                               \
    _Pragma("unroll")                                                         \
    for (int s = 0; s < 8; ++s) {                                             \
        int g    = (s << 2) + wv;                                             \
        int tsel = g >> 4;                                                    \
        int r0   = (g & 15) << 3;                                             \
        const unsigned short* src = tsel ? wtz : xf;                          \
        unsigned short*       dst = tsel ? &sW[bi][0] : &sX[bi][0];           \
        int rowg = tsel ? col0 : tok0;                                        \
        gll16(src + (size_t)(rowg + r0 + lrow8) * C_ + (k0v) + gch * 8,       \
              dst + r0 * 64);                                                 \
    }                                                                         \
} while (0)

    STAGE_QKV(0, 0);

    for (int k0 = 0; k0 < C_; k0 += 64) {
        const int cur = (k0 >> 6) & 1;
        __syncthreads();                 // drains vmcnt(0): buf[cur] ready
        if (k0 + 64 < C_) STAGE_QKV(k0 + 64, cur ^ 1);

        const unsigned short* Abuf = (z < 2) ? &sX[cur][0] : &sW[cur][0];
        const unsigned short* Bbuf = (z < 2) ? &sW[cur][0] : &sX[cur][0];

        half8 af[4][2], bf_[4][2];
#pragma unroll
        for (int i = 0; i < 4; i++)
#pragma unroll
            for (int s = 0; s < 2; s++) {
                af[i][s]  = *(const half8*)&Abuf[aoff[i][s]];
                bf_[i][s] = *(const half8*)&Bbuf[boff[i][s]];
            }
#pragma unroll
        for (int s = 0; s < 2; s++)
#pragma unroll
            for (int j = 0; j < 4; j++)
#pragma unroll
                for (int i = 0; i < 4; i++)
                    acc[i][j] = __builtin_amdgcn_mfma_f32_16x16x32_f16(
                        af[i][s], bf_[j][s], acc[i][j], 0, 0, 0);
    }
#undef STAGE_QKV

    if (z == 0) {
#pragma unroll
        for (int j = 0; j < 4; j++) {
            int col = col0 + wn * 64 + j * 16 + l15;
            int h = col >> 6, d = col & 63;
            float bs = bias[col];
#pragma unroll
            for (int i = 0; i < 4; i++) {
#pragma unroll
                for (int r = 0; r < 4; r++) {
                    int tok = tok0 + wm * 64 + i * 16 + quad * 4 + r;
                    int bidx = tok >> 11, t = tok & (T_ - 1);
                    qb[((size_t)(bidx * H_ + h) * T_ + t) * DH_ + d] =
                        f2h((acc[i][j][r] + bs) * 0.18033688011112042f);
                }
            }
        }
    } else if (z == 1) {
#pragma unroll
        for (int j = 0; j < 4; j++) {
            int col = col0 + wn * 64 + j * 16 + l15;
            int h = col >> 6, d = col & 63;
            float bs = bias[col];
#pragma unroll
            for (int i = 0; i < 4; i++) {
#pragma unroll
                for (int r = 0; r < 4; r++) {
                    int tok = tok0 + wm * 64 + i * 16 + quad * 4 + r;
                    int bidx = tok >> 11, t = tok & (T_ - 1);
                    kb[((size_t)(bidx * H_ + h) * T_ + t) * DH_ + d] =
                        f2h(acc[i][j][r] + bs);
                }
            }
        }
    } else {
        float mv4[4]; int bidx4[4], t4[4];
#pragma unroll
        for (int j = 0; j < 4; j++) {
            int tok = tok0 + wn * 64 + j * 16 + l15;
            bidx4[j] = tok >> 11; t4[j] = tok & (T_ - 1);
            mv4[j] = (maskp[bidx4[j] * T_ + t4[j]] != 0) ? 1.f : 0.f;
        }
#pragma unroll
        for (int i = 0; i < 4; i++) {
#pragma unroll
            for (int r = 0; r < 4; r++) {
                int col = col0 + wm * 64 + i * 16 + quad * 4 + r;
                int h = col >> 6, d = col & 63;
                float bs = bias[col];
#pragma unroll
                for (int j = 0; j < 4; j++) {
                    vt[((size_t)(bidx4[j] * H_ + h) * DH_ + d) * T_ + t4[j]] =
                        f2h((acc[i][j][r] + bs) * mv4[j]);
                }
            }
        }
    }
}

// ---------------------------------------------------------------------------
// Attention R23 (session-best total 166.58us): T15 software pipeline on the
// R18 structure. Two P states; per step, QK(kt+1)+softmax -> pa_next runs
// interleaved with PV(kt)+l(kt) consuming pa_cur. K staged one tile deeper
// than V; both 2-deep (32KB LDS), one __syncthreads per kt.
// ---------------------------------------------------------------------------
__global__ __launch_bounds__(256, 2) void attn_mfma_kernel(
    const unsigned short* __restrict__ qb,  // [32][2048][64] f16 (pre-scaled)
    const unsigned short* __restrict__ kb,  // [32][2048][64] f16
    const unsigned short* __restrict__ vt,  // [32][64][2048] f16 (mask-zeroed)
    const int* __restrict__ mask,           // [2][2048]
    const unsigned short* __restrict__ mb,  // [2][2048] f16 {0,1}
    float* __restrict__ out)                // [2][2048][1024]
{
    __shared__ unsigned short Ks[2][64 * 64];
    __shared__ unsigned short Vs[2][64 * 64];

    const int bh   = blockIdx.x;            // bh-major: same head -> same XCD
    const int b    = bh >> 4;
    const int h    = bh & 15;
    const int wv   = threadIdx.x >> 6;      // 0..3
    const int lane = threadIdx.x & 63;
    const int l31  = lane & 31;
    const int hi   = lane >> 5;
    const int l7b  = l31 & 7;               // row&7 for swizzled frag reads
    const int q0w  = blockIdx.y * 128 + wv * 32;

    const unsigned short* kbh = kb + (size_t)bh * T_ * DH_;
    const unsigned short* vbh = vt + (size_t)bh * DH_ * T_;
    const unsigned short* mbb = mb + b * T_;
    const int* __restrict__ mrow = mask + b * T_;

    // Q B-frags (32x32x16): B[k=dh][n=q]: lane n=l31, k = hi*8+j per m-chunk
    half8 qf[4];
#pragma unroll
    for (int m = 0; m < 4; ++m)
        qf[m] = *(const half8*)(qb + ((size_t)bh * T_ + q0w + l31) * DH_
                                + m * 16 + hi * 8);

    f32x16 o0, o1, lacc;
#pragma unroll
    for (int r = 0; r < 16; ++r) { o0[r] = 0.f; o1[r] = 0.f; lacc[r] = 0.f; }

    const int lrow = lane >> 3;
    const int gch  = (lane & 7) ^ lrow;

// QK(tile in KRDp) -> exp2 -> packed A-frags into PA[0..3]
#define QK_BLOCK(KRDp, PA) do {                                               \
    _Pragma("unroll")                                                         \
    for (int st = 0; st < 2; ++st) {                                          \
        f32x16 sa;                                                            \
        _Pragma("unroll") for (int r = 0; r < 16; ++r) sa[r] = 0.f;           \
        _Pragma("unroll") for (int m = 0; m < 4; ++m) {                       \
            half8 kf = *(const half8*)((KRDp) + (st * 32 + l31) * 64          \
                                       + (((m * 2 + hi) ^ l7b) * 8));         \
            sa = __builtin_amdgcn_mfma_f32_32x32x16_f16(kf, qf[m], sa, 0,0,0);\
        }                                                                     \
        float p[16];                                                          \
        _Pragma("unroll") for (int r = 0; r < 16; ++r)                        \
            p[r] = __builtin_amdgcn_exp2f(sa[r]);                             \
        _Pragma("unroll") for (int kh = 0; kh < 2; ++kh) {                    \
            unsigned w0 = pk2(p[kh * 8 + 0], p[kh * 8 + 1]);                  \
            unsigned w2 = pk2(p[kh * 8 + 4], p[kh * 8 + 5]);                  \
            unsigned w1 = pk2(p[kh * 8 + 2], p[kh * 8 + 3]);                  \
            unsigned w3 = pk2(p[kh * 8 + 6], p[kh * 8 + 7]);                  \
            plswap(w0, w2);                                                   \
            plswap(w1, w3);                                                   \
            union { unsigned u[4]; half8 hh; } cv;                            \
            cv.u[0] = w0; cv.u[1] = w1; cv.u[2] = w2; cv.u[3] = w3;           \
            (PA)[st * 2 + kh] = cv.hh;                                        \
        }                                                                     \
    }                                                                         \
} while (0)

// l(KT) += P.mask ; O += P(KT) x V(tile in VRDp)
#define PV_BLOCK(KT, VRDp, PAC) do {                                          \
    half8 bmx[4];                                                             \
    _Pragma("unroll") for (int c = 0; c < 4; ++c)                             \
        bmx[c] = *(const half8*)(mbb + (KT) * 64 + c * 16 + hi * 8);          \
    _Pragma("unroll") for (int c = 0; c < 4; ++c)                             \
        lacc = __builtin_amdgcn_mfma_f32_32x32x16_f16((PAC)[c], bmx[c],       \
                                                      lacc, 0, 0, 0);         \
    _Pragma("unroll") for (int c = 0; c < 4; ++c) {                           \
        half8 v0 = *(const half8*)((VRDp) + (l31) * 64                        \
                                   + (((c * 2 + hi) ^ l7b) * 8));             \
        half8 v1 = *(const half8*)((VRDp) + (32 + l31) * 64                   \
                                   + (((c * 2 + hi) ^ l7b) * 8));             \
        o0 = __builtin_amdgcn_mfma_f32_32x32x16_f16((PAC)[c], v0, o0, 0,0,0); \
        o1 = __builtin_amdgcn_mfma_f32_32x32x16_f16((PAC)[c], v1, o1, 0,0,0); \
    }                                                                         \
} while (0)

// one pipeline step KT: stage K(KT+2)->KD, V(KT+1)->VD; QK(KT+1)->PAN from KR;
// PV(KT)+l(KT) from PAC and VR. One barrier; QK and PV streams independent.
#define ATTN_STEP(KT, KD, KR, VD, VR, PAC, PAN, DOK) do {                     \
    __syncthreads();                                                          \
    {                                                                         \
        const int nbk = ((KT) + 2) * 64, nbv = ((KT) + 1) * 64;               \
        _Pragma("unroll") for (int s = 0; s < 4; ++s) {                       \
            int j = (wv << 2) + s, rb = j & 7;                                \
            if (j < 8) {                                                      \
                if (DOK) gll16(kbh + (size_t)(nbk + rb * 8 + lrow) * DH_      \
                               + gch * 8, &(KD)[rb * 512]);                   \
            } else {                                                          \
                gll16(vbh + (size_t)(rb * 8 + lrow) * T_ + nbv + gch * 8,     \
                      &(VD)[rb * 512]);                                       \
            }                                                                 \
        }                                                                     \
    }                                                                         \
    QK_BLOCK(&(KR)[0], PAN);                                                  \
    PV_BLOCK(KT, &(VR)[0], PAC);                                              \
} while (0)

    // prologue: stage K(0)->Ks[0], V(0)->Vs[0]; K(1)->Ks[1] (all 4 waves)
#pragma unroll
    for (int s = 0; s < 4; ++s) {
        int j = (wv << 2) + s, rb = j & 7;
        if (j < 8) gll16(kbh + (size_t)(rb * 8 + lrow) * DH_ + gch * 8, &Ks[0][rb * 512]);
        else       gll16(vbh + (size_t)(rb * 8 + lrow) * T_  + gch * 8, &Vs[0][rb * 512]);
    }
#pragma unroll
    for (int s = 0; s < 2; ++s) {
        int rb = (wv << 1) + s;
        gll16(kbh + (size_t)(64 + rb * 8 + lrow) * DH_ + gch * 8, &Ks[1][rb * 512]);
    }
    __syncthreads();

    half8 paA[4], paB[4];
    QK_BLOCK(&Ks[0][0], paA);           // P(0)

    for (int kt = 0; kt < 30; kt += 2) {
        ATTN_STEP(kt,     Ks[0], Ks[1], Vs[1], Vs[0], paA, paB, true);
        ATTN_STEP(kt + 1, Ks[1], Ks[0], Vs[0], Vs[1], paB, paA, true);
    }
    ATTN_STEP(30, Ks[0], Ks[1], Vs[1], Vs[0], paA, paB, false);

    // epilogue: PV(31) + l(31) from paB, V(31) in Vs[1]
    __syncthreads();
    PV_BLOCK(31, &Vs[1][0], paB);

#undef ATTN_STEP
#undef PV_BLOCK
#undef QK_BLOCK

    // Epilogue: C row r -> q = q0w + (r&3) + 8*(r>>2) + 4*hi; l[q] = lacc[r]
    // (present in every lane). Cols: d = nt*32 + l31.
#pragma unroll
    for (int r = 0; r < 16; ++r) {
        int q = q0w + (r & 3) + 8 * (r >> 2) + 4 * hi;
        float lv = lacc[r];
        float iv = (mrow[q] != 0 && lv > 0.f) ? (1.0f / lv) : 0.f;
        float* orow = out + ((size_t)(b * T_ + q)) * C_ + h * DH_;
        orow[l31]      = o0[r] * iv;
        orow[32 + l31] = o1[r] * iv;
    }
}

// ---------------------------------------------------------------------------
extern "C" void kernel_launch(void* const* d_in, const int* in_sizes, int n_in,
                              void* d_out, int out_size, void* d_ws, size_t ws_size,
                              hipStream_t stream)
{
    (void)in_sizes; (void)n_in; (void)out_size; (void)ws_size;
    const float* x  = (const float*)d_in[0];
    const float* Wq = (const float*)d_in[1];
    const float* bq = (const float*)d_in[2];
    const float* Wk = (const float*)d_in[3];
    const float* bk = (const float*)d_in[4];
    const float* Wv = (const float*)d_in[5];
    const float* bv = (const float*)d_in[6];
    const int* mask = (const int*)d_in[7];
    float* out = (float*)d_out;

    const size_t NX = (size_t)B_ * T_ * C_;          // 4 Mi elements
    unsigned short* xf = (unsigned short*)d_ws;       // 8 MB fp16 x
    unsigned short* wt = xf + NX;                     // 6 MB fp16 W^T x3
    unsigned short* qb = wt + (size_t)3 * C_ * C_;    // 8 MB (pre-scaled q)
    unsigned short* kb = qb + NX;                     // 8 MB
    unsigned short* vt = kb + NX;                     // 8 MB
    unsigned short* mb = vt + NX;                     // 8 KB

    prep_kernel<<<5120, 256, 0, stream>>>(x, xf, mask, mb, Wq, Wk, Wv, wt);
    qkv_mfma_kernel<<<768, 256, 0, stream>>>(
        xf, wt, bq, bk, bv, mask, qb, kb, vt);
    attn_mfma_kernel<<<dim3(32, 16), 256, 0, stream>>>(qb, kb, vt, mask, mb, out);
}

// Round 13
// 169.041 us; speedup vs baseline: 1.0388x; 1.0184x over previous
//
#include <hip/hip_runtime.h>

#define B_ 2
#define T_ 2048
#define C_ 1024
#define H_ 16
#define DH_ 64

typedef __attribute__((ext_vector_type(8))) _Float16 half8;  // 8 f16 (4 VGPRs)
typedef __attribute__((ext_vector_type(4))) _Float16 half4;  // 4 f16 (2 VGPRs)
typedef __attribute__((ext_vector_type(2))) __fp16 fp16x2;   // cvt_pkrtz result type
typedef __attribute__((ext_vector_type(4))) float f32x4;
typedef __attribute__((ext_vector_type(16))) float f32x16;

__device__ __forceinline__ unsigned short f2h(float f) {
    union { _Float16 h; unsigned short u; } cv; cv.h = (_Float16)f; return cv.u;
}
__device__ __forceinline__ unsigned pk2(float a, float b) {
    union { fp16x2 h; unsigned u; } cv;
    cv.h = __builtin_amdgcn_cvt_pkrtz(a, b);
    return cv.u;
}
// swap lanes 32-63 of a with lanes 0-31 of b (gfx950)
__device__ __forceinline__ void plswap(unsigned &a, unsigned &b) {
    asm volatile("v_permlane32_swap_b32 %0, %1" : "+v"(a), "+v"(b));
}

__device__ __forceinline__ void gll16(const void* g, void* l) {
    __builtin_amdgcn_global_load_lds(
        (const __attribute__((address_space(1))) void*)g,
        (__attribute__((address_space(3))) void*)l, 16, 0, 0);
}

// ---------------------------------------------------------------------------
// Prep (single launch): blocks [0,2048): x fp32->fp16 (+mask vec in block 0);
// blocks [2048, 5120): W transpose+convert -> Wt[z] (fp16 [N][K]).
// ---------------------------------------------------------------------------
__global__ __launch_bounds__(256) void prep_kernel(
    const float* __restrict__ x, unsigned short* __restrict__ xf,
    const int* __restrict__ mask, unsigned short* __restrict__ mb,
    const float* __restrict__ Wq, const float* __restrict__ Wk,
    const float* __restrict__ Wv, unsigned short* __restrict__ wt)
{
    __shared__ float tile[32][33];
    const int tid = threadIdx.x;

    if (blockIdx.x < 2048) {
        const size_t idx8 = ((size_t)blockIdx.x * 256 + tid) * 8;
        float4 v0 = *(const float4*)(x + idx8);
        float4 v1 = *(const float4*)(x + idx8 + 4);
        float f[8] = {v0.x, v0.y, v0.z, v0.w, v1.x, v1.y, v1.z, v1.w};
        unsigned short h[8];
#pragma unroll
        for (int i = 0; i < 8; i++) h[i] = f2h(f[i]);
        *(uint4*)(xf + idx8) = *(const uint4*)h;

        if (blockIdx.x == 0) {
#pragma unroll
            for (int j = 0; j < 16; j++) {
                int i = tid * 16 + j;               // covers B_*T_ = 4096
                mb[i] = (mask[i] != 0) ? (unsigned short)0x3C00 : (unsigned short)0;
            }
        }
    } else {
        const int idx = blockIdx.x - 2048;
        const int z   = idx >> 10;
        const int rem = idx & 1023;
        const int n0  = (rem & 31) * 32;
        const int k0  = (rem >> 5) * 32;
        const float* __restrict__ W = (z == 0) ? Wq : (z == 1) ? Wk : Wv;
        unsigned short* __restrict__ wtz = wt + (size_t)z * C_ * C_;
        const int tx = tid & 31;
        const int ty = tid >> 5;                    // 0..7
#pragma unroll
        for (int j = 0; j < 4; j++)
            tile[ty + j * 8][tx] = W[(size_t)(k0 + ty + j * 8) * C_ + n0 + tx];
        __syncthreads();
#pragma unroll
        for (int j = 0; j < 4; j++)
            wtz[(size_t)(n0 + ty + j * 8) * C_ + k0 + tx] = f2h(tile[tx][ty + j * 8]);
    }
}

// ---------------------------------------------------------------------------
// QKV projection R22 (kept from R6): 2D XCD tiling (8 tok x 12 yz per XCD)
// + double-buffered LDS (64KB): barrier -> issue STAGE(t+1) -> compute(t).
// ---------------------------------------------------------------------------
__global__ __launch_bounds__(256) void qkv_mfma_kernel(
    const unsigned short* __restrict__ xf, const unsigned short* __restrict__ wt,
    const float* __restrict__ bq, const float* __restrict__ bk,
    const float* __restrict__ bv, const int* __restrict__ maskp,
    unsigned short* __restrict__ qb, unsigned short* __restrict__ kb,
    unsigned short* __restrict__ vt)
{
    __shared__ unsigned short sX[2][128 * 64];
    __shared__ unsigned short sW[2][128 * 64];

    const int bid  = blockIdx.x;
    const int xcd  = bid & 7;            // HW: block bid runs on XCD bid%8
    const int idx  = bid >> 3;           // 0..95 within XCD
    const int tokl = idx / 12;           // 0..7  (tok-local, outer)
    const int yzl  = idx % 12;           // 0..11 (yz-local, inner -> W hot)
    const int tokb = (xcd >> 1) * 8 + tokl;   // 0..31
    const int yz   = (xcd & 1) * 12 + yzl;    // 0..23
    const int z    = yz >> 3;            // 0..2
    const int yb   = yz & 7;             // 0..7

    const float* __restrict__ bias = (z == 0) ? bq : (z == 1) ? bk : bv;
    const unsigned short* __restrict__ wtz = wt + (size_t)z * C_ * C_;

    const int tok0 = tokb * 128;
    const int col0 = yb * 128;
    const int wv    = threadIdx.x >> 6;
    const int lane  = threadIdx.x & 63;
    const int l15   = lane & 15;
    const int quad  = lane >> 4;
    const int l7    = l15 & 7;
    const int wm    = wv >> 1;
    const int wn    = wv & 1;
    const int lrow8 = lane >> 3;
    const int gch   = (lane & 7) ^ lrow8;

    f32x4 acc[4][4];
#pragma unroll
    for (int i = 0; i < 4; i++)
#pragma unroll
        for (int j = 0; j < 4; j++) acc[i][j] = (f32x4){0.f, 0.f, 0.f, 0.f};

    int aoff[4][2], boff[4][2];
#pragma unroll
    for (int i = 0; i < 4; i++)
#pragma unroll
        for (int s = 0; s < 2; s++) {
            aoff[i][s] = (wm * 64 + i * 16 + l15) * 64 + (((s * 4 + quad) ^ l7) * 8);
            boff[i][s] = (wn * 64 + i * 16 + l15) * 64 + (((s * 4 + quad) ^ l7) * 8);
        }

#define STAGE_QKV(k0v, bi) do {                                               \
    _Pragma("unroll")                                                         \
    for (int s = 0; s < 8; ++s) {                                             \
        int g    = (s << 2) + wv;                                             \
        int tsel = g >> 4;                                                    \
        int r0   = (g & 15) << 3;                                             \
        const unsigned short* src = tsel ? wtz : xf;                          \
        unsigned short*       dst = tsel ? &sW[bi][0] : &sX[bi][0];           \
        int rowg = tsel ? col0 : tok0;                                        \
        gll16(src + (size_t)(rowg + r0 + lrow8) * C_ + (k0v) + gch * 8,       \
              dst + r0 * 64);                                                 \
    }                                                                         \
} while (0)

    STAGE_QKV(0, 0);

    for (int k0 = 0; k0 < C_; k0 += 64) {
        const int cur = (k0 >> 6) & 1;
        __syncthreads();                 // drains vmcnt(0): buf[cur] ready
        if (k0 + 64 < C_) STAGE_QKV(k0 + 64, cur ^ 1);

        const unsigned short* Abuf = (z < 2) ? &sX[cur][0] : &sW[cur][0];
        const unsigned short* Bbuf = (z < 2) ? &sW[cur][0] : &sX[cur][0];

        half8 af[4][2], bf_[4][2];
#pragma unroll
        for (int i = 0; i < 4; i++)
#pragma unroll
            for (int s = 0; s < 2; s++) {
                af[i][s]  = *(const half8*)&Abuf[aoff[i][s]];
                bf_[i][s] = *(const half8*)&Bbuf[boff[i][s]];
            }
#pragma unroll
        for (int s = 0; s < 2; s++)
#pragma unroll
            for (int j = 0; j < 4; j++)
#pragma unroll
                for (int i = 0; i < 4; i++)
                    acc[i][j] = __builtin_amdgcn_mfma_f32_16x16x32_f16(
                        af[i][s], bf_[j][s], acc[i][j], 0, 0, 0);
    }
#undef STAGE_QKV

    if (z == 0) {
#pragma unroll
        for (int j = 0; j < 4; j++) {
            int col = col0 + wn * 64 + j * 16 + l15;
            int h = col >> 6, d = col & 63;
            float bs = bias[col];
#pragma unroll
            for (int i = 0; i < 4; i++) {
#pragma unroll
                for (int r = 0; r < 4; r++) {
                    int tok = tok0 + wm * 64 + i * 16 + quad * 4 + r;
                    int bidx = tok >> 11, t = tok & (T_ - 1);
                    qb[((size_t)(bidx * H_ + h) * T_ + t) * DH_ + d] =
                        f2h((acc[i][j][r] + bs) * 0.18033688011112042f);
                }
            }
        }
    } else if (z == 1) {
#pragma unroll
        for (int j = 0; j < 4; j++) {
            int col = col0 + wn * 64 + j * 16 + l15;
            int h = col >> 6, d = col & 63;
            float bs = bias[col];
#pragma unroll
            for (int i = 0; i < 4; i++) {
#pragma unroll
                for (int r = 0; r < 4; r++) {
                    int tok = tok0 + wm * 64 + i * 16 + quad * 4 + r;
                    int bidx = tok >> 11, t = tok & (T_ - 1);
                    kb[((size_t)(bidx * H_ + h) * T_ + t) * DH_ + d] =
                        f2h(acc[i][j][r] + bs);
                }
            }
        }
    } else {
        float mv4[4]; int bidx4[4], t4[4];
#pragma unroll
        for (int j = 0; j < 4; j++) {
            int tok = tok0 + wn * 64 + j * 16 + l15;
            bidx4[j] = tok >> 11; t4[j] = tok & (T_ - 1);
            mv4[j] = (maskp[bidx4[j] * T_ + t4[j]] != 0) ? 1.f : 0.f;
        }
#pragma unroll
        for (int i = 0; i < 4; i++) {
#pragma unroll
            for (int r = 0; r < 4; r++) {
                int col = col0 + wm * 64 + i * 16 + quad * 4 + r;
                int h = col >> 6, d = col & 63;
                float bs = bias[col];
#pragma unroll
                for (int j = 0; j < 4; j++) {
                    vt[((size_t)(bidx4[j] * H_ + h) * DH_ + d) * T_ + t4[j]] =
                        f2h((acc[i][j][r] + bs) * mv4[j]);
                }
            }
        }
    }
}

// ---------------------------------------------------------------------------
// Attention R28: R18 structure with KVBLK=128 (16 phases, 64KB LDS dbuf,
// still 2 blocks/CU) + 4-bit V swizzle.
// Mechanism 1: halve barrier count (each __syncthreads = vmcnt(0) drain +
// re-ramp; ~700cy/kt unattributed in the R6 pipe audit); 4 independent st
// chains per phase give the scheduler more interleave scope.
// Mechanism 2: V rows are now 256B = 16 chunks -> 4-bit XOR (chunk^(row&15))
// spreads 32 lanes over 16 slots = 2-way = free (m136), killing the V share
// of the structural 4-way b128 conflicts (K stays 4-way: only 8 chunks).
// Signature: SQ_LDS_BANK_CONFLICT 4.19M -> ~2.1M.
// ---------------------------------------------------------------------------
__global__ __launch_bounds__(256, 2) void attn_mfma_kernel(
    const unsigned short* __restrict__ qb,  // [32][2048][64] f16 (pre-scaled)
    const unsigned short* __restrict__ kb,  // [32][2048][64] f16
    const unsigned short* __restrict__ vt,  // [32][64][2048] f16 (mask-zeroed)
    const int* __restrict__ mask,           // [2][2048]
    const unsigned short* __restrict__ mb,  // [2][2048] f16 {0,1}
    float* __restrict__ out)                // [2][2048][1024]
{
    __shared__ unsigned short Ks[2][128 * 64];   // 128 keys x 64 dh (128B rows)
    __shared__ unsigned short Vs[2][64 * 128];   // 64 dh x 128 keys (256B rows)

    const int bh   = blockIdx.x;            // bh-major: same head -> same XCD
    const int b    = bh >> 4;
    const int h    = bh & 15;
    const int wv   = threadIdx.x >> 6;      // 0..3
    const int lane = threadIdx.x & 63;
    const int l31  = lane & 31;
    const int hi   = lane >> 5;
    const int l7b  = l31 & 7;               // K swizzle (8 chunks)
    const int l15b = l31 & 15;              // V swizzle (16 chunks)
    const int q0w  = blockIdx.y * 128 + wv * 32;

    const unsigned short* kbh = kb + (size_t)bh * T_ * DH_;
    const unsigned short* vbh = vt + (size_t)bh * DH_ * T_;
    const unsigned short* mbb = mb + b * T_;
    const int* __restrict__ mrow = mask + b * T_;

    // Q B-frags (32x32x16): B[k=dh][n=q]: lane n=l31, k = hi*8+j per m-chunk
    half8 qf[4];
#pragma unroll
    for (int m = 0; m < 4; ++m)
        qf[m] = *(const half8*)(qb + ((size_t)bh * T_ + q0w + l31) * DH_
                                + m * 16 + hi * 8);

    f32x16 o0, o1, lacc;
#pragma unroll
    for (int r = 0; r < 16; ++r) { o0[r] = 0.f; o1[r] = 0.f; lacc[r] = 0.f; }

    const int lrow  = lane >> 3;            // K staging: row within 8-row gll16
    const int gch   = (lane & 7) ^ lrow;    // K staging col swizzle (3-bit)
    const int vrow4 = lane >> 4;            // V staging: row within 4-row gll16
    const int vch   = lane & 15;            // V staging: storage chunk

    // Stage one 128-key tile: K = 16 gll16 (8 rows each), V = 16 gll16
    // (4 rows each, 4-bit chunk swizzle). 8 gll16 per wave.
#define STAGE_KV(kb0v, bi) do {                                               \
    _Pragma("unroll")                                                         \
    for (int s = 0; s < 8; ++s) {                                             \
        int j = (wv << 3) + s;                                                \
        if (j < 16) {                                                         \
            int rb = j;                                                       \
            gll16(kbh + (size_t)((kb0v) + rb * 8 + lrow) * DH_ + gch * 8,     \
                  &Ks[bi][rb * 512]);                                         \
        } else {                                                              \
            int rb = j - 16;                                                  \
            int vr = rb * 4 + vrow4;                                          \
            int gv = vch ^ (vr & 15);                                         \
            gll16(vbh + (size_t)vr * T_ + (kb0v) + gv * 8,                    \
                  &Vs[bi][rb * 512]);                                         \
        }                                                                     \
    }                                                                         \
} while (0)

    STAGE_KV(0, 0);

    for (int kt = 0; kt < 16; ++kt) {
        const int cur   = kt & 1;
        const int kbase = kt * 128;
        __syncthreads();

        if (kt < 15) STAGE_KV(kbase + 128, cur ^ 1);

        const unsigned short* Kc = &Ks[cur][0];
        const unsigned short* Vc = &Vs[cur][0];

        // mask B-frags: every column n holds m[k]; k = chunk*16 + hi*8 + j
        half8 bm[8];
#pragma unroll
        for (int c = 0; c < 8; ++c)
            bm[c] = *(const half8*)(mbb + kbase + c * 16 + hi * 8);

        // S^T = K . Q^T per 32-key sub-tile (st=0..3); exp2; pack A-frags.
        half8 pa[8];
#pragma unroll
        for (int st = 0; st < 4; ++st) {
            f32x16 sa;
#pragma unroll
            for (int r = 0; r < 16; ++r) sa[r] = 0.f;
#pragma unroll
            for (int m = 0; m < 4; ++m) {
                half8 kf = *(const half8*)(Kc + (st * 32 + l31) * 64
                                           + (((m * 2 + hi) ^ l7b) * 8));
                sa = __builtin_amdgcn_mfma_f32_32x32x16_f16(kf, qf[m], sa, 0, 0, 0);
            }
            float p[16];
#pragma unroll
            for (int r = 0; r < 16; ++r) p[r] = __builtin_amdgcn_exp2f(sa[r]);
            // C-layout k of reg r (rel. 16-key chunk): (r&3) + 8*(r>>2) + 4*hi.
            // swap(pk(p0,p1),pk(p4,p5))->w0,w2 ; swap(pk(p2,p3),pk(p6,p7))->w1,w3
#pragma unroll
            for (int kh = 0; kh < 2; ++kh) {
                unsigned w0 = pk2(p[kh * 8 + 0], p[kh * 8 + 1]);
                unsigned w2 = pk2(p[kh * 8 + 4], p[kh * 8 + 5]);
                unsigned w1 = pk2(p[kh * 8 + 2], p[kh * 8 + 3]);
                unsigned w3 = pk2(p[kh * 8 + 6], p[kh * 8 + 7]);
                plswap(w0, w2);
                plswap(w1, w3);
                union { unsigned u[4]; half8 hh; } cv;
                cv.u[0] = w0; cv.u[1] = w1; cv.u[2] = w2; cv.u[3] = w3;
                pa[st * 2 + kh] = cv.hh;
            }
        }

        // l += P . maskcol (all 32 output cols identical = l[q-row])
#pragma unroll
        for (int c = 0; c < 8; ++c)
            lacc = __builtin_amdgcn_mfma_f32_32x32x16_f16(pa[c], bm[c], lacc, 0, 0, 0);

        // O += P V. V B-frag: n = dh = l31 (+32), k = keys c*16+hi*8+j.
        // 4-bit swizzle: storage chunk = logical ^ (dh_row & 15) -> 2-way free.
#pragma unroll
        for (int c = 0; c < 8; ++c) {
            half8 v0 = *(const half8*)(Vc + (l31) * 128
                                       + (((c * 2 + hi) ^ l15b) * 8));
            half8 v1 = *(const half8*)(Vc + (32 + l31) * 128
                                       + (((c * 2 + hi) ^ l15b) * 8));
            o0 = __builtin_amdgcn_mfma_f32_32x32x16_f16(pa[c], v0, o0, 0, 0, 0);
            o1 = __builtin_amdgcn_mfma_f32_32x32x16_f16(pa[c], v1, o1, 0, 0, 0);
        }
    }
#undef STAGE_KV

    // Epilogue: C row r -> q = q0w + (r&3) + 8*(r>>2) + 4*hi; l[q] = lacc[r]
    // (present in every lane). Cols: d = nt*32 + l31.
#pragma unroll
    for (int r = 0; r < 16; ++r) {
        int q = q0w + (r & 3) + 8 * (r >> 2) + 4 * hi;
        float lv = lacc[r];
        float iv = (mrow[q] != 0 && lv > 0.f) ? (1.0f / lv) : 0.f;
        float* orow = out + ((size_t)(b * T_ + q)) * C_ + h * DH_;
        orow[l31]      = o0[r] * iv;
        orow[32 + l31] = o1[r] * iv;
    }
}

// ---------------------------------------------------------------------------
extern "C" void kernel_launch(void* const* d_in, const int* in_sizes, int n_in,
                              void* d_out, int out_size, void* d_ws, size_t ws_size,
                              hipStream_t stream)
{
    (void)in_sizes; (void)n_in; (void)out_size; (void)ws_size;
    const float* x  = (const float*)d_in[0];
    const float* Wq = (const float*)d_in[1];
    const float* bq = (const float*)d_in[2];
    const float* Wk = (const float*)d_in[3];
    const float* bk = (const float*)d_in[4];
    const float* Wv = (const float*)d_in[5];
    const float* bv = (const float*)d_in[6];
    const int* mask = (const int*)d_in[7];
    float* out = (float*)d_out;

    const size_t NX = (size_t)B_ * T_ * C_;          // 4 Mi elements
    unsigned short* xf = (unsigned short*)d_ws;       // 8 MB fp16 x
    unsigned short* wt = xf + NX;                     // 6 MB fp16 W^T x3
    unsigned short* qb = wt + (size_t)3 * C_ * C_;    // 8 MB (pre-scaled q)
    unsigned short* kb = qb + NX;                     // 8 MB
    unsigned short* vt = kb + NX;                     // 8 MB
    unsigned short* mb = vt + NX;                     // 8 KB

    prep_kernel<<<5120, 256, 0, stream>>>(x, xf, mask, mb, Wq, Wk, Wv, wt);
    qkv_mfma_kernel<<<768, 256, 0, stream>>>(
        xf, wt, bq, bk, bv, mask, qb, kb, vt);
    attn_mfma_kernel<<<dim3(32, 16), 256, 0, stream>>>(qb, kb, vt, mask, mb, out);
}

// Round 14
// 168.325 us; speedup vs baseline: 1.0432x; 1.0043x over previous
//
#include <hip/hip_runtime.h>

#define B_ 2
#define T_ 2048
#define C_ 1024
#define H_ 16
#define DH_ 64

typedef __attribute__((ext_vector_type(8))) _Float16 half8;  // 8 f16 (4 VGPRs)
typedef __attribute__((ext_vector_type(4))) _Float16 half4;  // 4 f16 (2 VGPRs)
typedef __attribute__((ext_vector_type(2))) __fp16 fp16x2;   // cvt_pkrtz result type
typedef __attribute__((ext_vector_type(4))) float f32x4;
typedef __attribute__((ext_vector_type(16))) float f32x16;

__device__ __forceinline__ unsigned short f2h(float f) {
    union { _Float16 h; unsigned short u; } cv; cv.h = (_Float16)f; return cv.u;
}
__device__ __forceinline__ unsigned pk2(float a, float b) {
    union { fp16x2 h; unsigned u; } cv;
    cv.h = __builtin_amdgcn_cvt_pkrtz(a, b);
    return cv.u;
}
// swap lanes 32-63 of a with lanes 0-31 of b (gfx950)
__device__ __forceinline__ void plswap(unsigned &a, unsigned &b) {
    asm volatile("v_permlane32_swap_b32 %0, %1" : "+v"(a), "+v"(b));
}

__device__ __forceinline__ void gll16(const void* g, void* l) {
    __builtin_amdgcn_global_load_lds(
        (const __attribute__((address_space(1))) void*)g,
        (__attribute__((address_space(3))) void*)l, 16, 0, 0);
}

// ---------------------------------------------------------------------------
// Prep (single launch): blocks [0,2048): x fp32->fp16 (+mask vec in block 0);
// blocks [2048, 5120): W transpose+convert -> Wt[z] (fp16 [N][K]).
// ---------------------------------------------------------------------------
__global__ __launch_bounds__(256) void prep_kernel(
    const float* __restrict__ x, unsigned short* __restrict__ xf,
    const int* __restrict__ mask, unsigned short* __restrict__ mb,
    const float* __restrict__ Wq, const float* __restrict__ Wk,
    const float* __restrict__ Wv, unsigned short* __restrict__ wt)
{
    __shared__ float tile[32][33];
    const int tid = threadIdx.x;

    if (blockIdx.x < 2048) {
        const size_t idx8 = ((size_t)blockIdx.x * 256 + tid) * 8;
        float4 v0 = *(const float4*)(x + idx8);
        float4 v1 = *(const float4*)(x + idx8 + 4);
        float f[8] = {v0.x, v0.y, v0.z, v0.w, v1.x, v1.y, v1.z, v1.w};
        unsigned short h[8];
#pragma unroll
        for (int i = 0; i < 8; i++) h[i] = f2h(f[i]);
        *(uint4*)(xf + idx8) = *(const uint4*)h;

        if (blockIdx.x == 0) {
#pragma unroll
            for (int j = 0; j < 16; j++) {
                int i = tid * 16 + j;               // covers B_*T_ = 4096
                mb[i] = (mask[i] != 0) ? (unsigned short)0x3C00 : (unsigned short)0;
            }
        }
    } else {
        const int idx = blockIdx.x - 2048;
        const int z   = idx >> 10;
        const int rem = idx & 1023;
        const int n0  = (rem & 31) * 32;
        const int k0  = (rem >> 5) * 32;
        const float* __restrict__ W = (z == 0) ? Wq : (z == 1) ? Wk : Wv;
        unsigned short* __restrict__ wtz = wt + (size_t)z * C_ * C_;
        const int tx = tid & 31;
        const int ty = tid >> 5;                    // 0..7
#pragma unroll
        for (int j = 0; j < 4; j++)
            tile[ty + j * 8][tx] = W[(size_t)(k0 + ty + j * 8) * C_ + n0 + tx];
        __syncthreads();
#pragma unroll
        for (int j = 0; j < 4; j++)
            wtz[(size_t)(n0 + ty + j * 8) * C_ + k0 + tx] = f2h(tile[tx][ty + j * 8]);
    }
}

// ---------------------------------------------------------------------------
// QKV projection R22 (kept from R6): 2D XCD tiling (8 tok x 12 yz per XCD)
// + double-buffered LDS (64KB): barrier -> issue STAGE(t+1) -> compute(t).
// ---------------------------------------------------------------------------
__global__ __launch_bounds__(256) void qkv_mfma_kernel(
    const unsigned short* __restrict__ xf, const unsigned short* __restrict__ wt,
    const float* __restrict__ bq, const float* __restrict__ bk,
    const float* __restrict__ bv, const int* __restrict__ maskp,
    unsigned short* __restrict__ qb, unsigned short* __restrict__ kb,
    unsigned short* __restrict__ vt)
{
    __shared__ unsigned short sX[2][128 * 64];
    __shared__ unsigned short sW[2][128 * 64];

    const int bid  = blockIdx.x;
    const int xcd  = bid & 7;            // HW: block bid runs on XCD bid%8
    const int idx  = bid >> 3;           // 0..95 within XCD
    const int tokl = idx / 12;           // 0..7  (tok-local, outer)
    const int yzl  = idx % 12;           // 0..11 (yz-local, inner -> W hot)
    const int tokb = (xcd >> 1) * 8 + tokl;   // 0..31
    const int yz   = (xcd & 1) * 12 + yzl;    // 0..23
    const int z    = yz >> 3;            // 0..2
    const int yb   = yz & 7;             // 0..7

    const float* __restrict__ bias = (z == 0) ? bq : (z == 1) ? bk : bv;
    const unsigned short* __restrict__ wtz = wt + (size_t)z * C_ * C_;

    const int tok0 = tokb * 128;
    const int col0 = yb * 128;
    const int wv    = threadIdx.x >> 6;
    const int lane  = threadIdx.x & 63;
    const int l15   = lane & 15;
    const int quad  = lane >> 4;
    const int l7    = l15 & 7;
    const int wm    = wv >> 1;
    const int wn    = wv & 1;
    const int lrow8 = lane >> 3;
    const int gch   = (lane & 7) ^ lrow8;

    f32x4 acc[4][4];
#pragma unroll
    for (int i = 0; i < 4; i++)
#pragma unroll
        for (int j = 0; j < 4; j++) acc[i][j] = (f32x4){0.f, 0.f, 0.f, 0.f};

    int aoff[4][2], boff[4][2];
#pragma unroll
    for (int i = 0; i < 4; i++)
#pragma unroll
        for (int s = 0; s < 2; s++) {
            aoff[i][s] = (wm * 64 + i * 16 + l15) * 64 + (((s * 4 + quad) ^ l7) * 8);
            boff[i][s] = (wn * 64 + i * 16 + l15) * 64 + (((s * 4 + quad) ^ l7) * 8);
        }

#define STAGE_QKV(k0v, bi) do {                                               \
    _Pragma("unroll")                                                         \
    for (int s = 0; s < 8; ++s) {                                             \
        int g    = (s << 2) + wv;                                             \
        int tsel = g >> 4;                                                    \
        int r0   = (g & 15) << 3;                                             \
        const unsigned short* src = tsel ? wtz : xf;                          \
        unsigned short*       dst = tsel ? &sW[bi][0] : &sX[bi][0];           \
        int rowg = tsel ? col0 : tok0;                                        \
        gll16(src + (size_t)(rowg + r0 + lrow8) * C_ + (k0v) + gch * 8,       \
              dst + r0 * 64);                                                 \
    }                                                                         \
} while (0)

    STAGE_QKV(0, 0);

    for (int k0 = 0; k0 < C_; k0 += 64) {
        const int cur = (k0 >> 6) & 1;
        __syncthreads();                 // drains vmcnt(0): buf[cur] ready
        if (k0 + 64 < C_) STAGE_QKV(k0 + 64, cur ^ 1);

        const unsigned short* Abuf = (z < 2) ? &sX[cur][0] : &sW[cur][0];
        const unsigned short* Bbuf = (z < 2) ? &sW[cur][0] : &sX[cur][0];

        half8 af[4][2], bf_[4][2];
#pragma unroll
        for (int i = 0; i < 4; i++)
#pragma unroll
            for (int s = 0; s < 2; s++) {
                af[i][s]  = *(const half8*)&Abuf[aoff[i][s]];
                bf_[i][s] = *(const half8*)&Bbuf[boff[i][s]];
            }
#pragma unroll
        for (int s = 0; s < 2; s++)
#pragma unroll
            for (int j = 0; j < 4; j++)
#pragma unroll
                for (int i = 0; i < 4; i++)
                    acc[i][j] = __builtin_amdgcn_mfma_f32_16x16x32_f16(
                        af[i][s], bf_[j][s], acc[i][j], 0, 0, 0);
    }
#undef STAGE_QKV

    if (z == 0) {
#pragma unroll
        for (int j = 0; j < 4; j++) {
            int col = col0 + wn * 64 + j * 16 + l15;
            int h = col >> 6, d = col & 63;
            float bs = bias[col];
#pragma unroll
            for (int i = 0; i < 4; i++) {
#pragma unroll
                for (int r = 0; r < 4; r++) {
                    int tok = tok0 + wm * 64 + i * 16 + quad * 4 + r;
                    int bidx = tok >> 11, t = tok & (T_ - 1);
                    qb[((size_t)(bidx * H_ + h) * T_ + t) * DH_ + d] =
                        f2h((acc[i][j][r] + bs) * 0.18033688011112042f);
                }
            }
        }
    } else if (z == 1) {
#pragma unroll
        for (int j = 0; j < 4; j++) {
            int col = col0 + wn * 64 + j * 16 + l15;
            int h = col >> 6, d = col & 63;
            float bs = bias[col];
#pragma unroll
            for (int i = 0; i < 4; i++) {
#pragma unroll
                for (int r = 0; r < 4; r++) {
                    int tok = tok0 + wm * 64 + i * 16 + quad * 4 + r;
                    int bidx = tok >> 11, t = tok & (T_ - 1);
                    kb[((size_t)(bidx * H_ + h) * T_ + t) * DH_ + d] =
                        f2h(acc[i][j][r] + bs);
                }
            }
        }
    } else {
        float mv4[4]; int bidx4[4], t4[4];
#pragma unroll
        for (int j = 0; j < 4; j++) {
            int tok = tok0 + wn * 64 + j * 16 + l15;
            bidx4[j] = tok >> 11; t4[j] = tok & (T_ - 1);
            mv4[j] = (maskp[bidx4[j] * T_ + t4[j]] != 0) ? 1.f : 0.f;
        }
#pragma unroll
        for (int i = 0; i < 4; i++) {
#pragma unroll
            for (int r = 0; r < 4; r++) {
                int col = col0 + wm * 64 + i * 16 + quad * 4 + r;
                int h = col >> 6, d = col & 63;
                float bs = bias[col];
#pragma unroll
                for (int j = 0; j < 4; j++) {
                    vt[((size_t)(bidx4[j] * H_ + h) * DH_ + d) * T_ + t4[j]] =
                        f2h((acc[i][j][r] + bs) * mv4[j]);
                }
            }
        }
    }
}

// ---------------------------------------------------------------------------
// Attention R23 (session-best config, measured 166.58us total / 53.2-53.4us
// attn dispatch): T15 software pipeline on the R18 32x32x16 structure.
// Two P states; per step, QK(kt+1)+softmax -> pa_next interleaved with
// PV(kt)+l(kt) consuming pa_cur. K staged one tile deeper than V; both
// 2-deep (32KB LDS), one __syncthreads per kt.
// Bracketing (13 rounds): q/wave {16,32,64} -> 32; KVBLK {64,128} -> 64;
// occupancy {1,2,4 blk/CU} -> 2; split-K, V-global, setprio, counted-vmcnt,
// conflict-free-V all <=0. This is the empirical optimum of the space.
// ---------------------------------------------------------------------------
__global__ __launch_bounds__(256, 2) void attn_mfma_kernel(
    const unsigned short* __restrict__ qb,  // [32][2048][64] f16 (pre-scaled)
    const unsigned short* __restrict__ kb,  // [32][2048][64] f16
    const unsigned short* __restrict__ vt,  // [32][64][2048] f16 (mask-zeroed)
    const int* __restrict__ mask,           // [2][2048]
    const unsigned short* __restrict__ mb,  // [2][2048] f16 {0,1}
    float* __restrict__ out)                // [2][2048][1024]
{
    __shared__ unsigned short Ks[2][64 * 64];
    __shared__ unsigned short Vs[2][64 * 64];

    const int bh   = blockIdx.x;            // bh-major: same head -> same XCD
    const int b    = bh >> 4;
    const int h    = bh & 15;
    const int wv   = threadIdx.x >> 6;      // 0..3
    const int lane = threadIdx.x & 63;
    const int l31  = lane & 31;
    const int hi   = lane >> 5;
    const int l7b  = l31 & 7;               // row&7 for swizzled frag reads
    const int q0w  = blockIdx.y * 128 + wv * 32;

    const unsigned short* kbh = kb + (size_t)bh * T_ * DH_;
    const unsigned short* vbh = vt + (size_t)bh * DH_ * T_;
    const unsigned short* mbb = mb + b * T_;
    const int* __restrict__ mrow = mask + b * T_;

    // Q B-frags (32x32x16): B[k=dh][n=q]: lane n=l31, k = hi*8+j per m-chunk
    half8 qf[4];
#pragma unroll
    for (int m = 0; m < 4; ++m)
        qf[m] = *(const half8*)(qb + ((size_t)bh * T_ + q0w + l31) * DH_
                                + m * 16 + hi * 8);

    f32x16 o0, o1, lacc;
#pragma unroll
    for (int r = 0; r < 16; ++r) { o0[r] = 0.f; o1[r] = 0.f; lacc[r] = 0.f; }

    const int lrow = lane >> 3;
    const int gch  = (lane & 7) ^ lrow;

// QK(tile in KRDp) -> exp2 -> packed A-frags into PA[0..3]
#define QK_BLOCK(KRDp, PA) do {                                               \
    _Pragma("unroll")                                                         \
    for (int st = 0; st < 2; ++st) {                                          \
        f32x16 sa;                                                            \
        _Pragma("unroll") for (int r = 0; r < 16; ++r) sa[r] = 0.f;           \
        _Pragma("unroll") for (int m = 0; m < 4; ++m) {                       \
            half8 kf = *(const half8*)((KRDp) + (st * 32 + l31) * 64          \
                                       + (((m * 2 + hi) ^ l7b) * 8));         \
            sa = __builtin_amdgcn_mfma_f32_32x32x16_f16(kf, qf[m], sa, 0,0,0);\
        }                                                                     \
        float p[16];                                                          \
        _Pragma("unroll") for (int r = 0; r < 16; ++r)                        \
            p[r] = __builtin_amdgcn_exp2f(sa[r]);                             \
        _Pragma("unroll") for (int kh = 0; kh < 2; ++kh) {                    \
            unsigned w0 = pk2(p[kh * 8 + 0], p[kh * 8 + 1]);                  \
            unsigned w2 = pk2(p[kh * 8 + 4], p[kh * 8 + 5]);                  \
            unsigned w1 = pk2(p[kh * 8 + 2], p[kh * 8 + 3]);                  \
            unsigned w3 = pk2(p[kh * 8 + 6], p[kh * 8 + 7]);                  \
            plswap(w0, w2);                                                   \
            plswap(w1, w3);                                                   \
            union { unsigned u[4]; half8 hh; } cv;                            \
            cv.u[0] = w0; cv.u[1] = w1; cv.u[2] = w2; cv.u[3] = w3;           \
            (PA)[st * 2 + kh] = cv.hh;                                        \
        }                                                                     \
    }                                                                         \
} while (0)

// l(KT) += P.mask ; O += P(KT) x V(tile in VRDp)
#define PV_BLOCK(KT, VRDp, PAC) do {                                          \
    half8 bmx[4];                                                             \
    _Pragma("unroll") for (int c = 0; c < 4; ++c)                             \
        bmx[c] = *(const half8*)(mbb + (KT) * 64 + c * 16 + hi * 8);          \
    _Pragma("unroll") for (int c = 0; c < 4; ++c)                             \
        lacc = __builtin_amdgcn_mfma_f32_32x32x16_f16((PAC)[c], bmx[c],       \
                                                      lacc, 0, 0, 0);         \
    _Pragma("unroll") for (int c = 0; c < 4; ++c) {                           \
        half8 v0 = *(const half8*)((VRDp) + (l31) * 64                        \
                                   + (((c * 2 + hi) ^ l7b) * 8));             \
        half8 v1 = *(const half8*)((VRDp) + (32 + l31) * 64                   \
                                   + (((c * 2 + hi) ^ l7b) * 8));             \
        o0 = __builtin_amdgcn_mfma_f32_32x32x16_f16((PAC)[c], v0, o0, 0,0,0); \
        o1 = __builtin_amdgcn_mfma_f32_32x32x16_f16((PAC)[c], v1, o1, 0,0,0); \
    }                                                                         \
} while (0)

// one pipeline step KT: stage K(KT+2)->KD, V(KT+1)->VD; QK(KT+1)->PAN from KR;
// PV(KT)+l(KT) from PAC and VR. One barrier; QK and PV streams independent.
#define ATTN_STEP(KT, KD, KR, VD, VR, PAC, PAN, DOK) do {                     \
    __syncthreads();                                                          \
    {                                                                         \
        const int nbk = ((KT) + 2) * 64, nbv = ((KT) + 1) * 64;               \
        _Pragma("unroll") for (int s = 0; s < 4; ++s) {                       \
            int j = (wv << 2) + s, rb = j & 7;                                \
            if (j < 8) {                                                      \
                if (DOK) gll16(kbh + (size_t)(nbk + rb * 8 + lrow) * DH_      \
                               + gch * 8, &(KD)[rb * 512]);                   \
            } else {                                                          \
                gll16(vbh + (size_t)(rb * 8 + lrow) * T_ + nbv + gch * 8,     \
                      &(VD)[rb * 512]);                                       \
            }                                                                 \
        }                                                                     \
    }                                                                         \
    QK_BLOCK(&(KR)[0], PAN);                                                  \
    PV_BLOCK(KT, &(VR)[0], PAC);                                              \
} while (0)

    // prologue: stage K(0)->Ks[0], V(0)->Vs[0]; K(1)->Ks[1] (all 4 waves)
#pragma unroll
    for (int s = 0; s < 4; ++s) {
        int j = (wv << 2) + s, rb = j & 7;
        if (j < 8) gll16(kbh + (size_t)(rb * 8 + lrow) * DH_ + gch * 8, &Ks[0][rb * 512]);
        else       gll16(vbh + (size_t)(rb * 8 + lrow) * T_  + gch * 8, &Vs[0][rb * 512]);
    }
#pragma unroll
    for (int s = 0; s < 2; ++s) {
        int rb = (wv << 1) + s;
        gll16(kbh + (size_t)(64 + rb * 8 + lrow) * DH_ + gch * 8, &Ks[1][rb * 512]);
    }
    __syncthreads();

    half8 paA[4], paB[4];
    QK_BLOCK(&Ks[0][0], paA);           // P(0)

    for (int kt = 0; kt < 30; kt += 2) {
        ATTN_STEP(kt,     Ks[0], Ks[1], Vs[1], Vs[0], paA, paB, true);
        ATTN_STEP(kt + 1, Ks[1], Ks[0], Vs[0], Vs[1], paB, paA, true);
    }
    ATTN_STEP(30, Ks[0], Ks[1], Vs[1], Vs[0], paA, paB, false);

    // epilogue: PV(31) + l(31) from paB, V(31) in Vs[1]
    __syncthreads();
    PV_BLOCK(31, &Vs[1][0], paB);

#undef ATTN_STEP
#undef PV_BLOCK
#undef QK_BLOCK

    // Epilogue: C row r -> q = q0w + (r&3) + 8*(r>>2) + 4*hi; l[q] = lacc[r]
    // (present in every lane). Cols: d = nt*32 + l31.
#pragma unroll
    for (int r = 0; r < 16; ++r) {
        int q = q0w + (r & 3) + 8 * (r >> 2) + 4 * hi;
        float lv = lacc[r];
        float iv = (mrow[q] != 0 && lv > 0.f) ? (1.0f / lv) : 0.f;
        float* orow = out + ((size_t)(b * T_ + q)) * C_ + h * DH_;
        orow[l31]      = o0[r] * iv;
        orow[32 + l31] = o1[r] * iv;
    }
}

// ---------------------------------------------------------------------------
extern "C" void kernel_launch(void* const* d_in, const int* in_sizes, int n_in,
                              void* d_out, int out_size, void* d_ws, size_t ws_size,
                              hipStream_t stream)
{
    (void)in_sizes; (void)n_in; (void)out_size; (void)ws_size;
    const float* x  = (const float*)d_in[0];
    const float* Wq = (const float*)d_in[1];
    const float* bq = (const float*)d_in[2];
    const float* Wk = (const float*)d_in[3];
    const float* bk = (const float*)d_in[4];
    const float* Wv = (const float*)d_in[5];
    const float* bv = (const float*)d_in[6];
    const int* mask = (const int*)d_in[7];
    float* out = (float*)d_out;

    const size_t NX = (size_t)B_ * T_ * C_;          // 4 Mi elements
    unsigned short* xf = (unsigned short*)d_ws;       // 8 MB fp16 x
    unsigned short* wt = xf + NX;                     // 6 MB fp16 W^T x3
    unsigned short* qb = wt + (size_t)3 * C_ * C_;    // 8 MB (pre-scaled q)
    unsigned short* kb = qb + NX;                     // 8 MB
    unsigned short* vt = kb + NX;                     // 8 MB
    unsigned short* mb = vt + NX;                     // 8 KB

    prep_kernel<<<5120, 256, 0, stream>>>(x, xf, mask, mb, Wq, Wk, Wv, wt);
    qkv_mfma_kernel<<<768, 256, 0, stream>>>(
        xf, wt, bq, bk, bv, mask, qb, kb, vt);
    attn_mfma_kernel<<<dim3(32, 16), 256, 0, stream>>>(qb, kb, vt, mask, mb, out);
}